// Round 2
// baseline (78.816 us; speedup 1.0000x reference)
//
#include <hip/hip_runtime.h>

// Problem constants (match reference)
constexpr int B = 8, Q = 900, K = 1203, N = 100;
constexpr float ALPHA = 0.25f, EPS = 1e-8f;
constexpr float COST_CLASS = 2.0f, COST_BBOX = 5.0f, COST_GIOU = 2.0f;

__global__ __launch_bounds__(256) void matcher_cost_kernel(
    const float* __restrict__ logits,   // (B,Q,K)
    const float* __restrict__ pboxes,   // (B,Q,4) cxcywh
    const int*   __restrict__ labels,   // (B,N)
    const float* __restrict__ tboxes,   // (B,N,4) cxcywh
    float* __restrict__ out)            // (B,Q,N)
{
    int idx = blockIdx.x * blockDim.x + threadIdx.x;
    constexpr int TOTAL = B * Q * N;
    if (idx >= TOTAL) return;

    int n  = idx % N;
    int bq = idx / N;          // b*Q + q
    int b  = bq / Q;

    // ---- class (focal) cost at gathered label ----
    int lab = labels[b * N + n];
    float x = logits[(size_t)bq * K + lab];
    float p   = 1.0f / (1.0f + expf(-x));
    float omp = 1.0f - p;
    float pos = -ALPHA * omp * omp * logf(fmaxf(p, EPS));
    float neg = -(1.0f - ALPHA) * p * p * logf(fmaxf(omp, EPS));
    float cls = pos - neg;

    // ---- boxes ----
    const float* pb = pboxes + (size_t)bq * 4;
    const float* tb = tboxes + ((size_t)b * N + n) * 4;
    float pcx = pb[0], pcy = pb[1], pw = pb[2], ph = pb[3];
    float tcx = tb[0], tcy = tb[1], tw = tb[2], th = tb[3];

    // L1 in cxcywh space
    float l1 = fabsf(pcx - tcx) + fabsf(pcy - tcy) + fabsf(pw - tw) + fabsf(ph - th);

    // convert to xyxy
    float px1 = pcx - 0.5f * pw, py1 = pcy - 0.5f * ph;
    float px2 = pcx + 0.5f * pw, py2 = pcy + 0.5f * ph;
    float tx1 = tcx - 0.5f * tw, ty1 = tcy - 0.5f * th;
    float tx2 = tcx + 0.5f * tw, ty2 = tcy + 0.5f * th;

    float area1 = (px2 - px1) * (py2 - py1);
    float area2 = (tx2 - tx1) * (ty2 - ty1);

    float iw = fmaxf(fminf(px2, tx2) - fmaxf(px1, tx1), 0.0f);
    float ih = fmaxf(fminf(py2, ty2) - fmaxf(py1, ty1), 0.0f);
    float inter = iw * ih;
    float uni   = area1 + area2 - inter;
    float iou   = inter / uni;

    float cw = fmaxf(fmaxf(px2, tx2) - fminf(px1, tx1), 0.0f);
    float ch = fmaxf(fmaxf(py2, ty2) - fminf(py1, ty1), 0.0f);
    float areac = cw * ch;
    float giou  = iou - (areac - uni) / areac;

    out[idx] = COST_CLASS * cls + COST_BBOX * l1 - COST_GIOU * giou;
}

extern "C" void kernel_launch(void* const* d_in, const int* in_sizes, int n_in,
                              void* d_out, int out_size, void* d_ws, size_t ws_size,
                              hipStream_t stream) {
    const float* logits = (const float*)d_in[0];
    const float* pboxes = (const float*)d_in[1];
    const int*   labels = (const int*)d_in[2];
    const float* tboxes = (const float*)d_in[3];
    float* out = (float*)d_out;

    constexpr int TOTAL = B * Q * N;          // 720000
    constexpr int BLOCK = 256;
    int grid = (TOTAL + BLOCK - 1) / BLOCK;   // 2813
    matcher_cost_kernel<<<grid, BLOCK, 0, stream>>>(logits, pboxes, labels, tboxes, out);
}